// Round 8
// baseline (376.307 us; speedup 1.0000x reference)
//
#include <hip/hip_runtime.h>
#include <hip/hip_bf16.h>

// MultiLoraLinear: out[b,s,o] = sum_i x[b,s,i] * weight[adapter_ids[b], o, i]
// B=4, S=2048, IN=4096, OUT=4096. fp32 in/out, bf16 MFMA compute.
// (1) cvt referenced adapters -> bf16 id-slots (dedup) in ws,
// (2) 256x256 GEMM, BK=32, ring-4 LDS, counted vmcnt, setprio.
//     A-path: fused fp32->bf16 reg-staging (global float4 -> pack -> ds_write).
//     B-path: global_load_lds width-16 from pre-converted bf16.

#define SEQ    2048
#define IN_K   4096
#define OUT_N  4096
#define NB     4

typedef __attribute__((ext_vector_type(8))) short  short8;   // bf16x8 MFMA frag
typedef __attribute__((ext_vector_type(4))) float  float4v;

constexpr int BM = 256, BN = 256, BK = 32;
constexpr int GT = 512;                 // 8 waves
constexpr int KTILES = IN_K / BK;       // 128

// bf16 RNE from f32
__device__ inline short f2b(float f) {
    union { float f; unsigned u; } v; v.f = f;
    unsigned r = v.u + 0x7FFFu + ((v.u >> 16) & 1u);
    return (short)(r >> 16);
}
__device__ inline short8 pack8(float4v lo, float4v hi) {
    short8 r;
    r[0] = f2b(lo[0]); r[1] = f2b(lo[1]); r[2] = f2b(lo[2]); r[3] = f2b(lo[3]);
    r[4] = f2b(hi[0]); r[5] = f2b(hi[1]); r[6] = f2b(hi[2]); r[7] = f2b(hi[3]);
    return r;
}

typedef const __attribute__((address_space(1))) void* gp1_t;
typedef __attribute__((address_space(3))) void*       lp3_t;
__device__ inline void gload_lds16(const void* g, void* l) {
    __builtin_amdgcn_global_load_lds((gp1_t)g, (lp3_t)l, 16, 0, 0);
}

#define WAITV(N)  asm volatile("s_waitcnt vmcnt(" #N ")" ::: "memory")
#define WAITL0()  asm volatile("s_waitcnt lgkmcnt(0)" ::: "memory")

// ---------------- pass 1: cvt referenced adapters fp32 -> bf16 ----------------
// by_id=1: write to slot ids[b] (dedup via first-occurrence); else slot b (gather).
__global__ __launch_bounds__(256)
void cvt_w_kernel(const float* __restrict__ w, const int* __restrict__ ids,
                  short* __restrict__ o, int by_id)
{
    const int b  = blockIdx.y;
    const int id = ids[b];
    int slot = b;
    if (by_id) {
        for (int j = 0; j < b; ++j) if (ids[j] == id) return;  // dup: already handled
        slot = id;
    }
    const float* __restrict__ src = w + (size_t)id   * OUT_N * IN_K;
    short* __restrict__       dst = o + (size_t)slot * OUT_N * IN_K;
    const int n8 = OUT_N * IN_K / 8;
    int i = blockIdx.x * blockDim.x + threadIdx.x;
    const int stride = gridDim.x * blockDim.x;
    for (; i < n8; i += stride) {
        const float4v a = *(const float4v*)(src + (size_t)i * 8);
        const float4v c = *(const float4v*)(src + (size_t)i * 8 + 4);
        *(short8*)(dst + (size_t)i * 8) = pack8(a, c);
    }
}

// ---------------- pass 2: 256^2 ring-4 GEMM, fused A conversion ----------------
// X: [NB][SEQ][IN_K] fp32; W: bf16 adapter slots; slot = by_id ? ids[bz] : bz.
// LDS granule swizzle: LDS granule c holds global (row=c>>2, kslot=(c&3)^((row>>1)&3)).
__global__ __launch_bounds__(GT, 2)
void mll_gemm_v8(const float* __restrict__ X, const short* __restrict__ W,
                 const int* __restrict__ ids, int by_id, float* __restrict__ out)
{
    // ring of 4 K-tile slots; slot s: A[256][32] bf16 then B[256][32] bf16 (32 KB)
    __shared__ __align__(16) short lds[4][2 * BM * BK];   // 128 KiB

    const int tid  = threadIdx.x;
    const int lane = tid & 63;
    const int wid  = tid >> 6;    // 0..7
    const int wr   = wid >> 2;    // 0..1  (M half)
    const int wc   = wid & 3;     // 0..3  (N quarter)

    // chunked XCD swizzle (512 blocks, 512 % 8 == 0 -> bijective)
    const int bid = blockIdx.x;
    const int n   = (bid & 7) * 64 + (bid >> 3);
    const int bx  = n & 15;          // OUT tile
    const int by  = (n >> 4) & 7;    // SEQ tile
    const int bz  = n >> 7;          // batch
    const int brow = by * BM, bcol = bx * BN;

    const int wslot = by_id ? ids[bz] : bz;
    const float* __restrict__ Xb = X + (size_t)bz * SEQ * IN_K + (size_t)brow * IN_K;
    const short* __restrict__ Bb = W + (size_t)wslot * OUT_N * IN_K + (size_t)bcol * IN_K;

    // staging chunks: per tile per operand 1024 x 16B(bf16); thread covers c0=tid, c1=tid+512
    // chunk c -> row c>>2, kslot (c&3)^((row>>1)&3); LDS dest linear at c*16B.
    const int c0 = tid, c1 = tid + GT;
    const int r0_ = c0 >> 2, s0_ = (c0 & 3) ^ ((r0_ >> 1) & 3);
    const int r1_ = c1 >> 2, s1_ = (c1 & 3) ^ ((r1_ >> 1) & 3);
    // A source: fp32, 8 floats (32B) per chunk
    const float* qa0 = Xb + (size_t)r0_ * IN_K + s0_ * 8;
    const float* qa1 = Xb + (size_t)r1_ * IN_K + s1_ * 8;
    // B source: bf16, 8 shorts (16B) per chunk
    const short* pb0 = Bb + (size_t)r0_ * IN_K + s0_ * 8;
    const short* pb1 = Bb + (size_t)r1_ * IN_K + s1_ * 8;

    float4v acc[8][4];
#pragma unroll
    for (int m = 0; m < 8; ++m)
#pragma unroll
        for (int q = 0; q < 4; ++q)
            acc[m][q] = (float4v){0.f, 0.f, 0.f, 0.f};

    const int lr  = lane & 15;
    const int ksl = lane >> 4;                      // 16B k-slot 0..3
    const int ks2 = (ksl ^ ((lr >> 1) & 3)) * 8;    // swizzled read k-offset (shorts)

    float4v rA[4];          // pending A fp32 (tile t+2's chunks: c0 lo/hi, c1 lo/hi)

    auto LOADA = [&](int kt) {
        const float* a0 = qa0 + kt * BK;
        const float* a1 = qa1 + kt * BK;
        rA[0] = *(const float4v*)a0;
        rA[1] = *(const float4v*)(a0 + 4);
        rA[2] = *(const float4v*)a1;
        rA[3] = *(const float4v*)(a1 + 4);
    };
    auto WRITEA = [&](int kt) {     // pack rA -> bf16, write slot kt&3 (linear dest)
        short* d = &lds[kt & 3][0];
        *(short8*)(d + c0 * 8) = pack8(rA[0], rA[1]);
        *(short8*)(d + c1 * 8) = pack8(rA[2], rA[3]);
    };
    auto GLOADB = [&](int kt) {
        short* d = &lds[kt & 3][0] + BM * BK;
        gload_lds16(pb0 + kt * BK, d + c0 * 8);
        gload_lds16(pb1 + kt * BK, d + c1 * 8);
    };

    // ---- prologue: A(0),A(1) via regs; B(0),B(1),B(2) via gload ----
    float4v rAa[4], rAb[4];
    {
        const float* a0 = qa0;             // tile 0
        const float* a1 = qa1;
        rAa[0] = *(const float4v*)a0;      rAa[1] = *(const float4v*)(a0 + 4);
        rAa[2] = *(const float4v*)a1;      rAa[3] = *(const float4v*)(a1 + 4);
        const float* b0 = qa0 + BK;        // tile 1
        const float* b1 = qa1 + BK;
        rAb[0] = *(const float4v*)b0;      rAb[1] = *(const float4v*)(b0 + 4);
        rAb[2] = *(const float4v*)b1;      rAb[3] = *(const float4v*)(b1 + 4);
    }
    GLOADB(0); GLOADB(1); GLOADB(2);       // 6 lds-loads
    WAITV(10);                             // A(0) fp32 (4) landed
    {
        short* d = &lds[0][0];
        *(short8*)(d + c0 * 8) = pack8(rAa[0], rAa[1]);
        *(short8*)(d + c1 * 8) = pack8(rAa[2], rAa[3]);
    }
    WAITV(6);                              // A(1) fp32 landed (leaves B0,B1,B2)
    {
        short* d = &lds[1][0];
        *(short8*)(d + c0 * 8) = pack8(rAb[0], rAb[1]);
        *(short8*)(d + c1 * 8) = pack8(rAb[2], rAb[3]);
    }
    WAITV(4);                              // B(0) landed (leaves B1,B2)
    WAITL0();                              // ds_writes drained for visibility
    __builtin_amdgcn_s_barrier();          // tile 0 fully certified

    short8 af_a[4], af_b[4], bf[4];
    {   // initial reads of tile 0
        const short* sA = &lds[0][0];
        const short* sB = sA + BM * BK;
#pragma unroll
        for (int m = 0; m < 4; ++m)
            af_a[m] = *(const short8*)(sA + (wr * 128 + m * 16 + lr) * BK + ks2);
#pragma unroll
        for (int q = 0; q < 4; ++q)
            bf[q] = *(const short8*)(sB + (wc * 64 + q * 16 + lr) * BK + ks2);
    }

    for (int t = 0; t < KTILES; ++t) {
        const short* sA = &lds[t & 3][0];

        // ---- phase A: MFMA m0..3; read af_b(t); cvt-write A(t+1); loadA(t+2) ----
        WAITL0();
        __builtin_amdgcn_s_setprio(1);
#pragma unroll
        for (int m = 0; m < 4; ++m)
#pragma unroll
            for (int q = 0; q < 4; ++q)
                acc[m][q] = __builtin_amdgcn_mfma_f32_16x16x32_bf16(
                    af_a[m], bf[q], acc[m][q], 0, 0, 0);
        __builtin_amdgcn_s_setprio(0);
#pragma unroll
        for (int m = 0; m < 4; ++m)
            af_b[m] = *(const short8*)(sA + (wr * 128 + (m + 4) * 16 + lr) * BK + ks2);

        // certify loadA(t+1) regs (pack source) AND B(t+1) (phase-B frag reads);
        // leaves only B(t+2) in flight (t<=125). t=126: B/A order flips -> full drain.
        if (t <= KTILES - 3)      WAITV(2);
        else if (t == KTILES - 2) WAITV(0);
        if (t >= 1 && t <= KTILES - 2) WRITEA(t + 1);   // pack + 2x ds_write_b128
        if (t + 2 < KTILES) LOADA(t + 2);               // 4x global fp32x4 (issue early)
        WAITL0();                      // ds_writes (and af_b reads) drained pre-barrier
        __builtin_amdgcn_s_barrier();  // A(t+1) visible to all waves; B(t+1) certified

        // ---- phase B: MFMA m4..7; read af_a+bf(t+1); gloadB(t+3) ----
        __builtin_amdgcn_s_setprio(1);
#pragma unroll
        for (int m = 0; m < 4; ++m)
#pragma unroll
            for (int q = 0; q < 4; ++q)
                acc[m + 4][q] = __builtin_amdgcn_mfma_f32_16x16x32_bf16(
                    af_b[m], bf[q], acc[m + 4][q], 0, 0, 0);
        __builtin_amdgcn_s_setprio(0);
        if (t < KTILES - 1) {
            const short* sN  = &lds[(t + 1) & 3][0];
            const short* sNB = sN + BM * BK;
#pragma unroll
            for (int m = 0; m < 4; ++m)
                af_a[m] = *(const short8*)(sN + (wr * 128 + m * 16 + lr) * BK + ks2);
#pragma unroll
            for (int q = 0; q < 4; ++q)
                bf[q] = *(const short8*)(sNB + (wc * 64 + q * 16 + lr) * BK + ks2);
        }
        if (t + 3 < KTILES) GLOADB(t + 3);
        __builtin_amdgcn_s_barrier();
    }

    // epilogue: C/D layout col=lane&15, row=(lane>>4)*4+reg
    float* __restrict__ ob = out + (size_t)bz * SEQ * OUT_N;
    const int lrow = ksl * 4;
#pragma unroll
    for (int m = 0; m < 8; ++m) {
#pragma unroll
        for (int q = 0; q < 4; ++q) {
            const int r0 = brow + wr * 128 + m * 16 + lrow;
            const int c  = bcol + wc * 64 + q * 16 + lr;
#pragma unroll
            for (int j = 0; j < 4; ++j)
                ob[(size_t)(r0 + j) * OUT_N + c] = acc[m][q][j];
        }
    }
}

// ---------------- fallback: fused kernel (ws too small) ----------------
__device__ inline int xr(int row) { return (row & 3) ^ ((row >> 2) & 3); }

__global__ __launch_bounds__(256, 2)
void mll_gemm_fused(const float* __restrict__ x,
                    const float* __restrict__ w,
                    const int*   __restrict__ adapter_ids,
                    float* __restrict__ out)
{
    constexpr int FBM = 128, FBN = 128, FBK = 32;
    __shared__ __align__(16) short As[2][FBM * FBK];
    __shared__ __align__(16) short Bs[2][FBN * FBK];

    const int tid  = threadIdx.x;
    const int lane = tid & 63;
    const int wave = tid >> 6;
    const int wr   = wave >> 1;
    const int wc   = wave & 1;

    const int b    = blockIdx.z;
    const int aid  = adapter_ids[b];
    const int brow = blockIdx.y * FBM;
    const int bcol = blockIdx.x * FBN;

    const float* __restrict__ xb = x + (size_t)b   * SEQ   * IN_K;
    const float* __restrict__ wb = w + (size_t)aid * OUT_N * IN_K;

    float4v ra[2][2], rb[2][2];

    auto LOADG = [&](int kt) {
        const int k0 = kt * FBK;
#pragma unroll
        for (int g = 0; g < 2; ++g) {
            const int f  = tid + g * 256;
            const int r  = f >> 2;
            const int sl = f & 3;
            const float* pa = xb + (size_t)(brow + r) * IN_K + k0 + sl * 8;
            ra[g][0] = *(const float4v*)pa;
            ra[g][1] = *(const float4v*)(pa + 4);
            const float* pb = wb + (size_t)(bcol + r) * IN_K + k0 + sl * 8;
            rb[g][0] = *(const float4v*)pb;
            rb[g][1] = *(const float4v*)(pb + 4);
        }
    };
    auto STORE_LDS = [&](int buf) {
#pragma unroll
        for (int g = 0; g < 2; ++g) {
            const int f  = tid + g * 256;
            const int r  = f >> 2;
            const int sl = f & 3;
            const int ss = sl ^ xr(r);
            *(short8*)&As[buf][r * FBK + ss * 8] = pack8(ra[g][0], ra[g][1]);
            *(short8*)&Bs[buf][r * FBK + ss * 8] = pack8(rb[g][0], rb[g][1]);
        }
    };

    float4v acc[4][4];
#pragma unroll
    for (int m = 0; m < 4; ++m)
#pragma unroll
        for (int q = 0; q < 4; ++q)
            acc[m][q] = (float4v){0.f, 0.f, 0.f, 0.f};

    const int NT = IN_K / FBK;
    LOADG(0); STORE_LDS(0); __syncthreads();
    int cur = 0;
    for (int kt = 0; kt < NT; ++kt) {
        if (kt + 1 < NT) LOADG(kt + 1);
        short8 af[4], bfr[4];
        const int ksl = lane >> 4;
#pragma unroll
        for (int m = 0; m < 4; ++m) {
            const int rrk = wr * 64 + m * 16 + (lane & 15);
            af[m] = *(const short8*)&As[cur][rrk * FBK + (ksl ^ xr(rrk)) * 8];
        }
#pragma unroll
        for (int q = 0; q < 4; ++q) {
            const int rc = wc * 64 + q * 16 + (lane & 15);
            bfr[q] = *(const short8*)&Bs[cur][rc * FBK + (ksl ^ xr(rc)) * 8];
        }
#pragma unroll
        for (int m = 0; m < 4; ++m)
#pragma unroll
            for (int q = 0; q < 4; ++q)
                acc[m][q] = __builtin_amdgcn_mfma_f32_16x16x32_bf16(
                    af[m], bfr[q], acc[m][q], 0, 0, 0);
        if (kt + 1 < NT) STORE_LDS(cur ^ 1);
        __syncthreads();
        cur ^= 1;
    }

    float* __restrict__ ob = out + (size_t)b * SEQ * OUT_N;
    const int lrow = (lane >> 4) * 4;
    const int lcol = lane & 15;
#pragma unroll
    for (int m = 0; m < 4; ++m) {
#pragma unroll
        for (int q = 0; q < 4; ++q) {
            const int r0 = brow + wr * 64 + m * 16 + lrow;
            const int c  = bcol + wc * 64 + q * 16 + lcol;
#pragma unroll
            for (int j = 0; j < 4; ++j)
                ob[(size_t)(r0 + j) * OUT_N + c] = acc[m][q][j];
        }
    }
}

extern "C" void kernel_launch(void* const* d_in, const int* in_sizes, int n_in,
                              void* d_out, int out_size, void* d_ws, size_t ws_size,
                              hipStream_t stream)
{
    const float* x   = (const float*)d_in[0];
    const float* w   = (const float*)d_in[1];
    const int*   ids = (const int*)d_in[2];
    float* out = (float*)d_out;

    const size_t wb4_bytes = (size_t)NB * OUT_N * IN_K * sizeof(short);  // 128 MB
    const size_t wb8_bytes = (size_t)8  * OUT_N * IN_K * sizeof(short);  // 256 MB

    if (ws_size >= wb8_bytes) {            // id-indexed slots + dedup
        short* wb16 = (short*)d_ws;
        cvt_w_kernel<<<dim3(1024, NB), 256, 0, stream>>>(w, ids, wb16, 1);
        mll_gemm_v8<<<512, GT, 0, stream>>>(x, wb16, ids, 1, out);
    } else if (ws_size >= wb4_bytes) {     // per-batch gather
        short* wb16 = (short*)d_ws;
        cvt_w_kernel<<<dim3(1024, NB), 256, 0, stream>>>(w, ids, wb16, 0);
        mll_gemm_v8<<<512, GT, 0, stream>>>(x, wb16, ids, 0, out);
    } else {
        mll_gemm_fused<<<dim3(OUT_N / 128, SEQ / 128, NB), 256, 0, stream>>>(
            x, w, ids, out);
    }
}

// Round 9
// 336.753 us; speedup vs baseline: 1.1175x; 1.1175x over previous
//
#include <hip/hip_runtime.h>
#include <hip/hip_bf16.h>

// MultiLoraLinear: out[b,s,o] = sum_i x[b,s,i] * weight[adapter_ids[b], o, i]
// B=4, S=2048, IN=4096, OUT=4096. fp32 in/out, bf16 MFMA compute.
// (1) cvt x -> bf16 ws, (2) cvt referenced adapters -> bf16 id-slots (dedup),
// (3) 256x256 GEMM, BK=64, A-ring-3 + B-ring-2 LDS (160 KB), ONE barrier and
//     ONE counted WAITV(4) per K-tile, 2x 32-MFMA clusters, setprio.

#define SEQ    2048
#define IN_K   4096
#define OUT_N  4096
#define NB     4

typedef __attribute__((ext_vector_type(8))) short  short8;   // bf16x8 MFMA frag
typedef __attribute__((ext_vector_type(4))) float  float4v;

constexpr int BM = 256, BN = 256, BK = 64;
constexpr int GT = 512;                 // 8 waves
constexpr int KT = IN_K / BK;           // 64 K-tiles

// bf16 RNE from f32
__device__ inline short f2b(float f) {
    union { float f; unsigned u; } v; v.f = f;
    unsigned r = v.u + 0x7FFFu + ((v.u >> 16) & 1u);
    return (short)(r >> 16);
}
__device__ inline short8 pack8(float4v lo, float4v hi) {
    short8 r;
    r[0] = f2b(lo[0]); r[1] = f2b(lo[1]); r[2] = f2b(lo[2]); r[3] = f2b(lo[3]);
    r[4] = f2b(hi[0]); r[5] = f2b(hi[1]); r[6] = f2b(hi[2]); r[7] = f2b(hi[3]);
    return r;
}

typedef const __attribute__((address_space(1))) void* gp1_t;
typedef __attribute__((address_space(3))) void*       lp3_t;
__device__ inline void gload_lds16(const void* g, void* l) {
    __builtin_amdgcn_global_load_lds((gp1_t)g, (lp3_t)l, 16, 0, 0);
}

#define WAITV(N)  asm volatile("s_waitcnt vmcnt(" #N ")" ::: "memory")

// ---------------- pass 1: x fp32 -> bf16 ----------------
__global__ __launch_bounds__(256)
void cvt_x_kernel(const float* __restrict__ x, short* __restrict__ o, int n8)
{
    int i = blockIdx.x * blockDim.x + threadIdx.x;
    const int stride = gridDim.x * blockDim.x;
    for (; i < n8; i += stride) {
        const float4v a = *(const float4v*)(x + (size_t)i * 8);
        const float4v b = *(const float4v*)(x + (size_t)i * 8 + 4);
        *(short8*)(o + (size_t)i * 8) = pack8(a, b);
    }
}

// ---------------- pass 2: cvt referenced adapters fp32 -> bf16 ----------------
// by_id=1: write to slot ids[b] (dedup via first-occurrence); else slot b (gather).
__global__ __launch_bounds__(256)
void cvt_w_kernel(const float* __restrict__ w, const int* __restrict__ ids,
                  short* __restrict__ o, int by_id)
{
    const int b  = blockIdx.y;
    const int id = ids[b];
    int slot = b;
    if (by_id) {
        for (int j = 0; j < b; ++j) if (ids[j] == id) return;  // dup: already handled
        slot = id;
    }
    const float* __restrict__ src = w + (size_t)id   * OUT_N * IN_K;
    short* __restrict__       dst = o + (size_t)slot * OUT_N * IN_K;
    const int n8 = OUT_N * IN_K / 8;
    int i = blockIdx.x * blockDim.x + threadIdx.x;
    const int stride = gridDim.x * blockDim.x;
    for (; i < n8; i += stride) {
        const float4v a = *(const float4v*)(src + (size_t)i * 8);
        const float4v c = *(const float4v*)(src + (size_t)i * 8 + 4);
        *(short8*)(dst + (size_t)i * 8) = pack8(a, c);
    }
}

// ---------------- pass 3: 256^2 GEMM, BK=64, A-ring3/B-ring2 ----------------
// A: [NB][SEQ][IN_K] bf16; W: bf16 adapter slots; slot = by_id ? ids[bz] : bz.
// Row = 64 bf16 = 8 x 16B slots. LDS slot s_lds holds global kslot s_g = s_lds^(row&7)
// (linear LDS dest for global_load_lds; source pre-swizzled; read applies same XOR).
__global__ __launch_bounds__(GT, 2)
void mll_gemm_v9(const short* __restrict__ A, const short* __restrict__ W,
                 const int* __restrict__ ids, int by_id, float* __restrict__ out)
{
    __shared__ __align__(16) short ldsA[3][BM * BK];   // 96 KiB, slot = t % 3
    __shared__ __align__(16) short ldsB[2][BN * BK];   // 64 KiB, slot = t & 1

    const int tid  = threadIdx.x;
    const int lane = tid & 63;
    const int wid  = tid >> 6;    // 0..7
    const int wr   = wid >> 2;    // 0..1  (M half, 128 rows)
    const int wc   = wid & 3;     // 0..3  (N quarter, 64 cols)

    // chunked XCD swizzle (512 blocks, 512 % 8 == 0 -> bijective)
    const int bid = blockIdx.x;
    const int n   = (bid & 7) * 64 + (bid >> 3);
    const int bx  = n & 15;          // OUT tile
    const int by  = (n >> 4) & 7;    // SEQ tile
    const int bz  = n >> 7;          // batch
    const int brow = by * BM, bcol = bx * BN;

    const int wslot = by_id ? ids[bz] : bz;
    const short* __restrict__ Ab = A + (size_t)bz * SEQ * IN_K + (size_t)brow * IN_K;
    const short* __restrict__ Bb = W + (size_t)wslot * OUT_N * IN_K + (size_t)bcol * IN_K;

    // staging: per tile per operand 2048 x 16B chunks; thread covers c = tid + k*512
    // chunk c -> row c>>3, s_lds c&7, global kslot (c&7)^(row&7).
    int          offs[4];
    const short* pA[4];
    const short* pB[4];
#pragma unroll
    for (int k = 0; k < 4; ++k) {
        const int c   = tid + k * GT;
        const int row = c >> 3;
        const int sg  = (c & 7) ^ (row & 7);
        offs[k] = c * 8;                       // LDS offset in shorts (16B chunks)
        pA[k] = Ab + (size_t)row * IN_K + sg * 8;
        pB[k] = Bb + (size_t)row * IN_K + sg * 8;
    }

    float4v acc[8][4];
#pragma unroll
    for (int m = 0; m < 8; ++m)
#pragma unroll
        for (int q = 0; q < 4; ++q)
            acc[m][q] = (float4v){0.f, 0.f, 0.f, 0.f};

    const int lr  = lane & 15;
    const int ksl = lane >> 4;                          // 16B slot within K=32
    const int sw  = lr & 7;                             // row&7 == lr&7 (bases %8==0)
    const int o0  = ((0 + ksl) ^ sw) * 8;               // kstep 0 read offset (shorts)
    const int o1  = ((4 + ksl) ^ sw) * 8;               // kstep 1 read offset

    // per-frag LDS row bases (shorts; row stride 64)
    const int baseA = (wr * 128 + lr) * BK;             // + m*16*64
    const int baseB = (wc * 64  + lr) * BK;             // + q*16*64

    short8 fA0[8], fA1[8], fB0[4], fB1[4];

    // ---- prologue: stage A0,B0,A1,B1,A2 (20 loads) ----
#pragma unroll
    for (int k = 0; k < 4; ++k) gload_lds16(pA[k],          &ldsA[0][offs[k]]);
#pragma unroll
    for (int k = 0; k < 4; ++k) gload_lds16(pB[k],          &ldsB[0][offs[k]]);
#pragma unroll
    for (int k = 0; k < 4; ++k) gload_lds16(pA[k] + BK,     &ldsA[1][offs[k]]);
#pragma unroll
    for (int k = 0; k < 4; ++k) gload_lds16(pB[k] + BK,     &ldsB[1][offs[k]]);
#pragma unroll
    for (int k = 0; k < 4; ++k) gload_lds16(pA[k] + 2 * BK, &ldsA[2][offs[k]]);
    WAITV(12);                      // A0,B0 landed; A1,B1,A2 in flight
    __builtin_amdgcn_s_barrier();

    {   // kstep-0 frags of tile 0
        const short* sAp = &ldsA[0][0];
        const short* sBp = &ldsB[0][0];
#pragma unroll
        for (int m = 0; m < 8; ++m)
            fA0[m] = *(const short8*)(sAp + baseA + m * 16 * BK + o0);
#pragma unroll
        for (int q = 0; q < 4; ++q)
            fB0[q] = *(const short8*)(sBp + baseB + q * 16 * BK + o0);
    }

    int sa = 0;                     // t % 3
    for (int t = 0; t < KT; ++t) {
        const short* sAp = &ldsA[sa][0];
        const short* sBp = &ldsB[t & 1][0];

        // ---- phase A: 32 MFMA kstep0; read kstep1 frags; stage B(t+1) ----
        __builtin_amdgcn_s_setprio(1);
#pragma unroll
        for (int m = 0; m < 8; ++m)
#pragma unroll
            for (int q = 0; q < 4; ++q)
                acc[m][q] = __builtin_amdgcn_mfma_f32_16x16x32_bf16(
                    fA0[m], fB0[q], acc[m][q], 0, 0, 0);
        __builtin_amdgcn_s_setprio(0);
#pragma unroll
        for (int m = 0; m < 8; ++m)
            fA1[m] = *(const short8*)(sAp + baseA + m * 16 * BK + o1);
#pragma unroll
        for (int q = 0; q < 4; ++q)
            fB1[q] = *(const short8*)(sBp + baseB + q * 16 * BK + o1);
        if (t >= 1 && t + 1 < KT) {             // stage B(t+1) into other B buf
            short* d = &ldsB[(t + 1) & 1][0];
#pragma unroll
            for (int k = 0; k < 4; ++k)
                gload_lds16(pB[k] + (t + 1) * BK, d + offs[k]);
        }

        // ---- phase B: 32 MFMA kstep1; stage A(t+2) ----
        __builtin_amdgcn_s_setprio(1);
#pragma unroll
        for (int m = 0; m < 8; ++m)
#pragma unroll
            for (int q = 0; q < 4; ++q)
                acc[m][q] = __builtin_amdgcn_mfma_f32_16x16x32_bf16(
                    fA1[m], fB1[q], acc[m][q], 0, 0, 0);
        __builtin_amdgcn_s_setprio(0);
        int sa2 = sa + 2; if (sa2 >= 3) sa2 -= 3;
        if (t >= 1 && t + 2 < KT) {             // stage A(t+2), 2-tile lead
            short* d = &ldsA[sa2][0];
#pragma unroll
            for (int k = 0; k < 4; ++k)
                gload_lds16(pA[k] + (t + 2) * BK, d + offs[k]);
        }

        // ---- boundary: certify A(t+1)+B(t+1); keep A(t+2) in flight ----
        if (t <= KT - 3)      WAITV(4);
        else if (t == KT - 2) WAITV(0);
        if (t < KT - 1) {
            __builtin_amdgcn_s_barrier();
            int sn = sa + 1; if (sn >= 3) sn -= 3;
            const short* nA = &ldsA[sn][0];
            const short* nB = &ldsB[(t + 1) & 1][0];
#pragma unroll
            for (int m = 0; m < 8; ++m)
                fA0[m] = *(const short8*)(nA + baseA + m * 16 * BK + o0);
#pragma unroll
            for (int q = 0; q < 4; ++q)
                fB0[q] = *(const short8*)(nB + baseB + q * 16 * BK + o0);
            sa = sn;
        }
    }

    // epilogue: C/D layout col=lane&15, row=(lane>>4)*4+reg
    float* __restrict__ ob = out + (size_t)bz * SEQ * OUT_N;
    const int lrow = ksl * 4;
#pragma unroll
    for (int m = 0; m < 8; ++m) {
#pragma unroll
        for (int q = 0; q < 4; ++q) {
            const int r0 = brow + wr * 128 + m * 16 + lrow;
            const int c  = bcol + wc * 64 + q * 16 + lr;
#pragma unroll
            for (int j = 0; j < 4; ++j)
                ob[(size_t)(r0 + j) * OUT_N + c] = acc[m][q][j];
        }
    }
}

// ---------------- fallback: fused kernel (ws too small) ----------------
__device__ inline int xr(int row) { return (row & 3) ^ ((row >> 2) & 3); }

__global__ __launch_bounds__(256, 2)
void mll_gemm_fused(const float* __restrict__ x,
                    const float* __restrict__ w,
                    const int*   __restrict__ adapter_ids,
                    float* __restrict__ out)
{
    constexpr int FBM = 128, FBN = 128, FBK = 32;
    __shared__ __align__(16) short As[2][FBM * FBK];
    __shared__ __align__(16) short Bs[2][FBN * FBK];

    const int tid  = threadIdx.x;
    const int lane = tid & 63;
    const int wave = tid >> 6;
    const int wr   = wave >> 1;
    const int wc   = wave & 1;

    const int b    = blockIdx.z;
    const int aid  = adapter_ids[b];
    const int brow = blockIdx.y * FBM;
    const int bcol = blockIdx.x * FBN;

    const float* __restrict__ xb = x + (size_t)b   * SEQ   * IN_K;
    const float* __restrict__ wb = w + (size_t)aid * OUT_N * IN_K;

    float4v ra[2][2], rb[2][2];

    auto LOADG = [&](int kt) {
        const int k0 = kt * FBK;
#pragma unroll
        for (int g = 0; g < 2; ++g) {
            const int f  = tid + g * 256;
            const int r  = f >> 2;
            const int sl = f & 3;
            const float* pa = xb + (size_t)(brow + r) * IN_K + k0 + sl * 8;
            ra[g][0] = *(const float4v*)pa;
            ra[g][1] = *(const float4v*)(pa + 4);
            const float* pb = wb + (size_t)(bcol + r) * IN_K + k0 + sl * 8;
            rb[g][0] = *(const float4v*)pb;
            rb[g][1] = *(const float4v*)(pb + 4);
        }
    };
    auto STORE_LDS = [&](int buf) {
#pragma unroll
        for (int g = 0; g < 2; ++g) {
            const int f  = tid + g * 256;
            const int r  = f >> 2;
            const int sl = f & 3;
            const int ss = sl ^ xr(r);
            *(short8*)&As[buf][r * FBK + ss * 8] = pack8(ra[g][0], ra[g][1]);
            *(short8*)&Bs[buf][r * FBK + ss * 8] = pack8(rb[g][0], rb[g][1]);
        }
    };

    float4v acc[4][4];
#pragma unroll
    for (int m = 0; m < 4; ++m)
#pragma unroll
        for (int q = 0; q < 4; ++q)
            acc[m][q] = (float4v){0.f, 0.f, 0.f, 0.f};

    const int NT = IN_K / FBK;
    LOADG(0); STORE_LDS(0); __syncthreads();
    int cur = 0;
    for (int kt = 0; kt < NT; ++kt) {
        if (kt + 1 < NT) LOADG(kt + 1);
        short8 af[4], bfr[4];
        const int ksl = lane >> 4;
#pragma unroll
        for (int m = 0; m < 4; ++m) {
            const int rrk = wr * 64 + m * 16 + (lane & 15);
            af[m] = *(const short8*)&As[cur][rrk * FBK + (ksl ^ xr(rrk)) * 8];
        }
#pragma unroll
        for (int q = 0; q < 4; ++q) {
            const int rc = wc * 64 + q * 16 + (lane & 15);
            bfr[q] = *(const short8*)&Bs[cur][rc * FBK + (ksl ^ xr(rc)) * 8];
        }
#pragma unroll
        for (int m = 0; m < 4; ++m)
#pragma unroll
            for (int q = 0; q < 4; ++q)
                acc[m][q] = __builtin_amdgcn_mfma_f32_16x16x32_bf16(
                    af[m], bfr[q], acc[m][q], 0, 0, 0);
        if (kt + 1 < NT) STORE_LDS(cur ^ 1);
        __syncthreads();
        cur ^= 1;
    }

    float* __restrict__ ob = out + (size_t)b * SEQ * OUT_N;
    const int lrow = (lane >> 4) * 4;
    const int lcol = lane & 15;
#pragma unroll
    for (int m = 0; m < 4; ++m) {
#pragma unroll
        for (int q = 0; q < 4; ++q) {
            const int r0 = brow + wr * 64 + m * 16 + lrow;
            const int c  = bcol + wc * 64 + q * 16 + lcol;
#pragma unroll
            for (int j = 0; j < 4; ++j)
                ob[(size_t)(r0 + j) * OUT_N + c] = acc[m][q][j];
        }
    }
}

extern "C" void kernel_launch(void* const* d_in, const int* in_sizes, int n_in,
                              void* d_out, int out_size, void* d_ws, size_t ws_size,
                              hipStream_t stream)
{
    const float* x   = (const float*)d_in[0];
    const float* w   = (const float*)d_in[1];
    const int*   ids = (const int*)d_in[2];
    float* out = (float*)d_out;

    const size_t xb_bytes  = (size_t)NB * SEQ   * IN_K * sizeof(short);  //  64 MB
    const size_t wb4_bytes = (size_t)NB * OUT_N * IN_K * sizeof(short);  // 128 MB
    const size_t wb8_bytes = (size_t)8  * OUT_N * IN_K * sizeof(short);  // 256 MB

    if (ws_size >= xb_bytes + wb8_bytes) {          // id-indexed slots + dedup
        short* xb16 = (short*)d_ws;
        short* wb16 = (short*)((char*)d_ws + xb_bytes);
        cvt_x_kernel<<<2048, 256, 0, stream>>>(x, xb16, NB * SEQ * IN_K / 8);
        cvt_w_kernel<<<dim3(1024, NB), 256, 0, stream>>>(w, ids, wb16, 1);
        mll_gemm_v9<<<512, GT, 0, stream>>>(xb16, wb16, ids, 1, out);
    } else if (ws_size >= xb_bytes + wb4_bytes) {   // per-batch gather
        short* xb16 = (short*)d_ws;
        short* wb16 = (short*)((char*)d_ws + xb_bytes);
        cvt_x_kernel<<<2048, 256, 0, stream>>>(x, xb16, NB * SEQ * IN_K / 8);
        cvt_w_kernel<<<dim3(1024, NB), 256, 0, stream>>>(w, ids, wb16, 0);
        mll_gemm_v9<<<512, GT, 0, stream>>>(xb16, wb16, ids, 0, out);
    } else {
        mll_gemm_fused<<<dim3(OUT_N / 128, SEQ / 128, NB), 256, 0, stream>>>(
            x, w, ids, out);
    }
}

// Round 10
// 331.762 us; speedup vs baseline: 1.1343x; 1.0150x over previous
//
#include <hip/hip_runtime.h>
#include <hip/hip_bf16.h>

// MultiLoraLinear: out[b,s,o] = sum_i x[b,s,i] * weight[adapter_ids[b], o, i]
// B=4, S=2048, IN=4096, OUT=4096. fp32 in/out, bf16 MFMA compute.
// (1) cvt x -> bf16 ws, (2) cvt referenced adapters -> bf16 id-slots (dedup),
// (3) 256x256 GEMM, BK=64, m201-style 8-phase schedule: 2 dbuf x 4 chunks
//     (A0,A1,B0,B1; 16KB each), per-phase {reads | 1 half-tile stage | bar |
//     lgkm0 | setprio | 16-MFMA quadrant | bar}, vmcnt(4) once per K-tile.

#define SEQ    2048
#define IN_K   4096
#define OUT_N  4096
#define NB     4

typedef __attribute__((ext_vector_type(8))) short  short8;   // bf16x8 MFMA frag
typedef __attribute__((ext_vector_type(4))) float  float4v;

constexpr int BM = 256, BN = 256, BK = 64;
constexpr int GT = 512;                 // 8 waves
constexpr int KT = IN_K / BK;           // 64 K-tiles
constexpr int CH = 128 * 64;            // chunk size in shorts (16 KB)

// bf16 RNE from f32
__device__ inline short f2b(float f) {
    union { float f; unsigned u; } v; v.f = f;
    unsigned r = v.u + 0x7FFFu + ((v.u >> 16) & 1u);
    return (short)(r >> 16);
}
__device__ inline short8 pack8(float4v lo, float4v hi) {
    short8 r;
    r[0] = f2b(lo[0]); r[1] = f2b(lo[1]); r[2] = f2b(lo[2]); r[3] = f2b(lo[3]);
    r[4] = f2b(hi[0]); r[5] = f2b(hi[1]); r[6] = f2b(hi[2]); r[7] = f2b(hi[3]);
    return r;
}

typedef const __attribute__((address_space(1))) void* gp1_t;
typedef __attribute__((address_space(3))) void*       lp3_t;
__device__ inline void gload_lds16(const void* g, void* l) {
    __builtin_amdgcn_global_load_lds((gp1_t)g, (lp3_t)l, 16, 0, 0);
}

#define WAITV(N)  asm volatile("s_waitcnt vmcnt(" #N ")" ::: "memory")
#define WAITL0()  asm volatile("s_waitcnt lgkmcnt(0)" ::: "memory")
#define BAR()     __builtin_amdgcn_s_barrier()

// ---------------- pass 1: x fp32 -> bf16 ----------------
__global__ __launch_bounds__(256)
void cvt_x_kernel(const float* __restrict__ x, short* __restrict__ o, int n8)
{
    int i = blockIdx.x * blockDim.x + threadIdx.x;
    const int stride = gridDim.x * blockDim.x;
    for (; i < n8; i += stride) {
        const float4v a = *(const float4v*)(x + (size_t)i * 8);
        const float4v b = *(const float4v*)(x + (size_t)i * 8 + 4);
        *(short8*)(o + (size_t)i * 8) = pack8(a, b);
    }
}

// ---------------- pass 2: cvt referenced adapters fp32 -> bf16 ----------------
// by_id=1: write to slot ids[b] (dedup via first-occurrence); else slot b (gather).
__global__ __launch_bounds__(256)
void cvt_w_kernel(const float* __restrict__ w, const int* __restrict__ ids,
                  short* __restrict__ o, int by_id)
{
    const int b  = blockIdx.y;
    const int id = ids[b];
    int slot = b;
    if (by_id) {
        for (int j = 0; j < b; ++j) if (ids[j] == id) return;  // dup: already handled
        slot = id;
    }
    const float* __restrict__ src = w + (size_t)id   * OUT_N * IN_K;
    short* __restrict__       dst = o + (size_t)slot * OUT_N * IN_K;
    const int n8 = OUT_N * IN_K / 8;
    int i = blockIdx.x * blockDim.x + threadIdx.x;
    const int stride = gridDim.x * blockDim.x;
    for (; i < n8; i += stride) {
        const float4v a = *(const float4v*)(src + (size_t)i * 8);
        const float4v c = *(const float4v*)(src + (size_t)i * 8 + 4);
        *(short8*)(dst + (size_t)i * 8) = pack8(a, c);
    }
}

// ---------------- pass 3: 256^2 GEMM, 8-phase template ----------------
// A: [NB][SEQ][IN_K] bf16; W: bf16 adapter slots; slot = by_id ? ids[bz] : bz.
// Chunk layout [128 rows][8 x 16B slots]; LDS slot s holds global kslot s^(row&7).
__global__ __launch_bounds__(GT, 2)
void mll_gemm_v10(const short* __restrict__ A, const short* __restrict__ W,
                  const int* __restrict__ ids, int by_id, float* __restrict__ out)
{
    // [buf][chunk: 0=A0,1=A1,2=B0,3=B1][128*64 shorts] = 128 KiB
    __shared__ __align__(16) short lds[2][4][CH];

    const int tid  = threadIdx.x;
    const int lane = tid & 63;
    const int wid  = tid >> 6;    // 0..7
    const int wr   = wid >> 2;    // 0..1  (M half -> A chunk wr)
    const int wc   = wid & 3;     // 0..3  (N quarter -> B chunk 2+(wc>>1))

    // chunked XCD swizzle (512 blocks, 512 % 8 == 0 -> bijective)
    const int bid = blockIdx.x;
    const int n   = (bid & 7) * 64 + (bid >> 3);
    const int bx  = n & 15;          // OUT tile
    const int by  = (n >> 4) & 7;    // SEQ tile
    const int bz  = n >> 7;          // batch
    const int brow = by * BM, bcol = bx * BN;

    const int wslot = by_id ? ids[bz] : bz;
    const short* __restrict__ Ab = A + (size_t)bz * SEQ * IN_K + (size_t)brow * IN_K;
    const short* __restrict__ Bb = W + (size_t)wslot * OUT_N * IN_K + (size_t)bcol * IN_K;

    // staging: per chunk 1024 x 16B; thread covers c = tid + r*512, r=0,1.
    // c -> row c>>3, LDS slot c&7, global kslot (c&7)^(row&7). Linear LDS dest.
    const short* gA[2][2];   // [half][r]
    const short* gB[2][2];
    int ldso[2];
#pragma unroll
    for (int r = 0; r < 2; ++r) {
        const int c   = tid + r * GT;
        const int row = c >> 3;
        const int sg  = (c & 7) ^ (row & 7);
        ldso[r] = c * 8;
        gA[0][r] = Ab + (size_t)row         * IN_K + sg * 8;
        gA[1][r] = Ab + (size_t)(128 + row) * IN_K + sg * 8;
        gB[0][r] = Bb + (size_t)row         * IN_K + sg * 8;
        gB[1][r] = Bb + (size_t)(128 + row) * IN_K + sg * 8;
    }

#define STAGE_A(h, t) do { short* d_ = &lds[(t) & 1][h][0];                    \
        gload_lds16(gA[h][0] + (t) * BK, d_ + ldso[0]);                        \
        gload_lds16(gA[h][1] + (t) * BK, d_ + ldso[1]); } while (0)
#define STAGE_B(h, t) do { short* d_ = &lds[(t) & 1][2 + (h)][0];              \
        gload_lds16(gB[h][0] + (t) * BK, d_ + ldso[0]);                        \
        gload_lds16(gB[h][1] + (t) * BK, d_ + ldso[1]); } while (0)

    float4v acc[8][4];
#pragma unroll
    for (int m = 0; m < 8; ++m)
#pragma unroll
        for (int q = 0; q < 4; ++q)
            acc[m][q] = (float4v){0.f, 0.f, 0.f, 0.f};

    const int lr  = lane & 15;
    const int ksl = lane >> 4;                       // 16B slot within K=32 half
    const int sw  = lr & 7;
    const int so0 = ((0 + ksl) ^ sw) * 8;            // khalf 0 read offset (shorts)
    const int so1 = ((4 + ksl) ^ sw) * 8;            // khalf 1

    const int cA = wr;                 // this wave's A chunk
    const int cB = 2 + (wc >> 1);      // this wave's B chunk
    const int bRow0 = ((wc & 1) * 64 + lr) * BK;     // B row base (q adds q*16*BK)

    short8 fA[4][2], fBlo[2][2], fBhi[2][2];

    // ---- prologue: stage tiles 0 and 1 fully (16 loads) ----
    STAGE_A(0, 0); STAGE_A(1, 0); STAGE_B(0, 0); STAGE_B(1, 0);
    STAGE_A(0, 1); STAGE_A(1, 1); STAGE_B(0, 1); STAGE_B(1, 1);
    WAITV(8);                       // tile 0 certified; tile 1 in flight
    BAR();

    for (int t = 0; t < KT; ++t) {
        const short* sA = &lds[t & 1][cA][0];
        const short* sB = &lds[t & 1][cB][0];

        // ===== P1: read A(mlo)x2 + B(qlo)x2 (12); stage A0(t+1); MFMA mlo x qlo =====
#pragma unroll
        for (int m = 0; m < 4; ++m) {
            fA[m][0] = *(const short8*)(sA + (m * 16 + lr) * BK + so0);
            fA[m][1] = *(const short8*)(sA + (m * 16 + lr) * BK + so1);
        }
#pragma unroll
        for (int q = 0; q < 2; ++q) {
            fBlo[q][0] = *(const short8*)(sB + bRow0 + q * 16 * BK + so0);
            fBlo[q][1] = *(const short8*)(sB + bRow0 + q * 16 * BK + so1);
        }
        if (t >= 1 && t + 1 < KT) STAGE_A(0, t + 1);
        BAR(); WAITL0();
        __builtin_amdgcn_s_setprio(1);
#pragma unroll
        for (int m = 0; m < 4; ++m)
#pragma unroll
            for (int q = 0; q < 2; ++q) {
                acc[m][q] = __builtin_amdgcn_mfma_f32_16x16x32_bf16(
                    fA[m][0], fBlo[q][0], acc[m][q], 0, 0, 0);
                acc[m][q] = __builtin_amdgcn_mfma_f32_16x16x32_bf16(
                    fA[m][1], fBlo[q][1], acc[m][q], 0, 0, 0);
            }
        __builtin_amdgcn_s_setprio(0);
        BAR();

        // ===== P2: read B(qhi) (4); stage A1(t+1); MFMA mlo x qhi =====
#pragma unroll
        for (int q = 0; q < 2; ++q) {
            fBhi[q][0] = *(const short8*)(sB + bRow0 + (q + 2) * 16 * BK + so0);
            fBhi[q][1] = *(const short8*)(sB + bRow0 + (q + 2) * 16 * BK + so1);
        }
        if (t >= 1 && t + 1 < KT) STAGE_A(1, t + 1);
        BAR(); WAITL0();
        __builtin_amdgcn_s_setprio(1);
#pragma unroll
        for (int m = 0; m < 4; ++m)
#pragma unroll
            for (int q = 0; q < 2; ++q) {
                acc[m][q + 2] = __builtin_amdgcn_mfma_f32_16x16x32_bf16(
                    fA[m][0], fBhi[q][0], acc[m][q + 2], 0, 0, 0);
                acc[m][q + 2] = __builtin_amdgcn_mfma_f32_16x16x32_bf16(
                    fA[m][1], fBhi[q][1], acc[m][q + 2], 0, 0, 0);
            }
        __builtin_amdgcn_s_setprio(0);
        BAR();

        // ===== P3: read A(mhi) (8, reuse fA); stage B0(t+2); MFMA mhi x qhi =====
#pragma unroll
        for (int m = 0; m < 4; ++m) {
            fA[m][0] = *(const short8*)(sA + ((m + 4) * 16 + lr) * BK + so0);
            fA[m][1] = *(const short8*)(sA + ((m + 4) * 16 + lr) * BK + so1);
        }
        if (t + 2 < KT) STAGE_B(0, t + 2);
        BAR(); WAITL0();
        __builtin_amdgcn_s_setprio(1);
#pragma unroll
        for (int m = 0; m < 4; ++m)
#pragma unroll
            for (int q = 0; q < 2; ++q) {
                acc[m + 4][q + 2] = __builtin_amdgcn_mfma_f32_16x16x32_bf16(
                    fA[m][0], fBhi[q][0], acc[m + 4][q + 2], 0, 0, 0);
                acc[m + 4][q + 2] = __builtin_amdgcn_mfma_f32_16x16x32_bf16(
                    fA[m][1], fBhi[q][1], acc[m + 4][q + 2], 0, 0, 0);
            }
        __builtin_amdgcn_s_setprio(0);
        BAR();

        // ===== P4: no reads; stage B1(t+2); vmcnt; MFMA mhi x qlo =====
        if (t + 2 < KT) STAGE_B(1, t + 2);
        if (t <= KT - 3)      WAITV(4);   // certify tile t+1; leave B(t+2) in flight
        else if (t == KT - 2) WAITV(0);
        BAR();
        __builtin_amdgcn_s_setprio(1);
#pragma unroll
        for (int m = 0; m < 4; ++m)
#pragma unroll
            for (int q = 0; q < 2; ++q) {
                acc[m + 4][q] = __builtin_amdgcn_mfma_f32_16x16x32_bf16(
                    fA[m][0], fBlo[q][0], acc[m + 4][q], 0, 0, 0);
                acc[m + 4][q] = __builtin_amdgcn_mfma_f32_16x16x32_bf16(
                    fA[m][1], fBlo[q][1], acc[m + 4][q], 0, 0, 0);
            }
        __builtin_amdgcn_s_setprio(0);
        BAR();
    }

    // epilogue: C/D layout col=lane&15, row=(lane>>4)*4+reg
    float* __restrict__ ob = out + (size_t)bz * SEQ * OUT_N;
    const int lrow = ksl * 4;
#pragma unroll
    for (int m = 0; m < 8; ++m) {
#pragma unroll
        for (int q = 0; q < 4; ++q) {
            const int r0 = brow + wr * 128 + m * 16 + lrow;
            const int c  = bcol + wc * 64 + q * 16 + lr;
#pragma unroll
            for (int j = 0; j < 4; ++j)
                ob[(size_t)(r0 + j) * OUT_N + c] = acc[m][q][j];
        }
    }
#undef STAGE_A
#undef STAGE_B
}

// ---------------- fallback: fused kernel (ws too small) ----------------
__device__ inline int xr(int row) { return (row & 3) ^ ((row >> 2) & 3); }

__global__ __launch_bounds__(256, 2)
void mll_gemm_fused(const float* __restrict__ x,
                    const float* __restrict__ w,
                    const int*   __restrict__ adapter_ids,
                    float* __restrict__ out)
{
    constexpr int FBM = 128, FBN = 128, FBK = 32;
    __shared__ __align__(16) short As[2][FBM * FBK];
    __shared__ __align__(16) short Bs[2][FBN * FBK];

    const int tid  = threadIdx.x;
    const int lane = tid & 63;
    const int wave = tid >> 6;
    const int wr   = wave >> 1;
    const int wc   = wave & 1;

    const int b    = blockIdx.z;
    const int aid  = adapter_ids[b];
    const int brow = blockIdx.y * FBM;
    const int bcol = blockIdx.x * FBN;

    const float* __restrict__ xb = x + (size_t)b   * SEQ   * IN_K;
    const float* __restrict__ wb = w + (size_t)aid * OUT_N * IN_K;

    float4v ra[2][2], rb[2][2];

    auto LOADG = [&](int kt) {
        const int k0 = kt * FBK;
#pragma unroll
        for (int g = 0; g < 2; ++g) {
            const int f  = tid + g * 256;
            const int r  = f >> 2;
            const int sl = f & 3;
            const float* pa = xb + (size_t)(brow + r) * IN_K + k0 + sl * 8;
            ra[g][0] = *(const float4v*)pa;
            ra[g][1] = *(const float4v*)(pa + 4);
            const float* pb = wb + (size_t)(bcol + r) * IN_K + k0 + sl * 8;
            rb[g][0] = *(const float4v*)pb;
            rb[g][1] = *(const float4v*)(pb + 4);
        }
    };
    auto STORE_LDS = [&](int buf) {
#pragma unroll
        for (int g = 0; g < 2; ++g) {
            const int f  = tid + g * 256;
            const int r  = f >> 2;
            const int sl = f & 3;
            const int ss = sl ^ xr(r);
            *(short8*)&As[buf][r * FBK + ss * 8] = pack8(ra[g][0], ra[g][1]);
            *(short8*)&Bs[buf][r * FBK + ss * 8] = pack8(rb[g][0], rb[g][1]);
        }
    };

    float4v acc[4][4];
#pragma unroll
    for (int m = 0; m < 4; ++m)
#pragma unroll
        for (int q = 0; q < 4; ++q)
            acc[m][q] = (float4v){0.f, 0.f, 0.f, 0.f};

    const int NT = IN_K / FBK;
    LOADG(0); STORE_LDS(0); __syncthreads();
    int cur = 0;
    for (int kt = 0; kt < NT; ++kt) {
        if (kt + 1 < NT) LOADG(kt + 1);
        short8 af[4], bfr[4];
        const int ksl = lane >> 4;
#pragma unroll
        for (int m = 0; m < 4; ++m) {
            const int rrk = wr * 64 + m * 16 + (lane & 15);
            af[m] = *(const short8*)&As[cur][rrk * FBK + (ksl ^ xr(rrk)) * 8];
        }
#pragma unroll
        for (int q = 0; q < 4; ++q) {
            const int rc = wc * 64 + q * 16 + (lane & 15);
            bfr[q] = *(const short8*)&Bs[cur][rc * FBK + (ksl ^ xr(rc)) * 8];
        }
#pragma unroll
        for (int m = 0; m < 4; ++m)
#pragma unroll
            for (int q = 0; q < 4; ++q)
                acc[m][q] = __builtin_amdgcn_mfma_f32_16x16x32_bf16(
                    af[m], bfr[q], acc[m][q], 0, 0, 0);
        if (kt + 1 < NT) STORE_LDS(cur ^ 1);
        __syncthreads();
        cur ^= 1;
    }

    float* __restrict__ ob = out + (size_t)b * SEQ * OUT_N;
    const int lrow = (lane >> 4) * 4;
    const int lcol = lane & 15;
#pragma unroll
    for (int m = 0; m < 4; ++m) {
#pragma unroll
        for (int q = 0; q < 4; ++q) {
            const int r0 = brow + wr * 64 + m * 16 + lrow;
            const int c  = bcol + wc * 64 + q * 16 + lcol;
#pragma unroll
            for (int j = 0; j < 4; ++j)
                ob[(size_t)(r0 + j) * OUT_N + c] = acc[m][q][j];
        }
    }
}

extern "C" void kernel_launch(void* const* d_in, const int* in_sizes, int n_in,
                              void* d_out, int out_size, void* d_ws, size_t ws_size,
                              hipStream_t stream)
{
    const float* x   = (const float*)d_in[0];
    const float* w   = (const float*)d_in[1];
    const int*   ids = (const int*)d_in[2];
    float* out = (float*)d_out;

    const size_t xb_bytes  = (size_t)NB * SEQ   * IN_K * sizeof(short);  //  64 MB
    const size_t wb4_bytes = (size_t)NB * OUT_N * IN_K * sizeof(short);  // 128 MB
    const size_t wb8_bytes = (size_t)8  * OUT_N * IN_K * sizeof(short);  // 256 MB

    if (ws_size >= xb_bytes + wb8_bytes) {          // id-indexed slots + dedup
        short* xb16 = (short*)d_ws;
        short* wb16 = (short*)((char*)d_ws + xb_bytes);
        cvt_x_kernel<<<2048, 256, 0, stream>>>(x, xb16, NB * SEQ * IN_K / 8);
        cvt_w_kernel<<<dim3(1024, NB), 256, 0, stream>>>(w, ids, wb16, 1);
        mll_gemm_v10<<<512, GT, 0, stream>>>(xb16, wb16, ids, 1, out);
    } else if (ws_size >= xb_bytes + wb4_bytes) {   // per-batch gather
        short* xb16 = (short*)d_ws;
        short* wb16 = (short*)((char*)d_ws + xb_bytes);
        cvt_x_kernel<<<2048, 256, 0, stream>>>(x, xb16, NB * SEQ * IN_K / 8);
        cvt_w_kernel<<<dim3(1024, NB), 256, 0, stream>>>(w, ids, wb16, 0);
        mll_gemm_v10<<<512, GT, 0, stream>>>(xb16, wb16, ids, 0, out);
    } else {
        mll_gemm_fused<<<dim3(OUT_N / 128, SEQ / 128, NB), 256, 0, stream>>>(
            x, w, ids, out);
    }
}

// Round 11
// 322.675 us; speedup vs baseline: 1.1662x; 1.0282x over previous
//
#include <hip/hip_runtime.h>
#include <hip/hip_bf16.h>

// MultiLoraLinear: out[b,s,o] = sum_i x[b,s,i] * weight[adapter_ids[b], o, i]
// B=4, S=2048, IN=4096, OUT=4096. fp32 in/out, bf16 MFMA compute.
// (1) one merged cvt kernel: x -> bf16 + referenced adapters -> bf16 id-slots,
// (2) 256x256 GEMM, BK=64, m201 8-phase schedule with: pre-barrier lgkm hints,
//     reduced barrier set (P2 closer only), vmcnt(4) once per K-tile, setprio.

#define SEQ    2048
#define IN_K   4096
#define OUT_N  4096
#define NB     4

typedef __attribute__((ext_vector_type(8))) short  short8;   // bf16x8 MFMA frag
typedef __attribute__((ext_vector_type(4))) float  float4v;

constexpr int BM = 256, BN = 256, BK = 64;
constexpr int GT = 512;                 // 8 waves
constexpr int KT = IN_K / BK;           // 64 K-tiles
constexpr int CH = 128 * 64;            // chunk size in shorts (16 KB)

// bf16 RNE from f32
__device__ inline short f2b(float f) {
    union { float f; unsigned u; } v; v.f = f;
    unsigned r = v.u + 0x7FFFu + ((v.u >> 16) & 1u);
    return (short)(r >> 16);
}
__device__ inline short8 pack8(float4v lo, float4v hi) {
    short8 r;
    r[0] = f2b(lo[0]); r[1] = f2b(lo[1]); r[2] = f2b(lo[2]); r[3] = f2b(lo[3]);
    r[4] = f2b(hi[0]); r[5] = f2b(hi[1]); r[6] = f2b(hi[2]); r[7] = f2b(hi[3]);
    return r;
}

typedef const __attribute__((address_space(1))) void* gp1_t;
typedef __attribute__((address_space(3))) void*       lp3_t;
__device__ inline void gload_lds16(const void* g, void* l) {
    __builtin_amdgcn_global_load_lds((gp1_t)g, (lp3_t)l, 16, 0, 0);
}

#define WAITV(N)  asm volatile("s_waitcnt vmcnt(" #N ")" ::: "memory")
#define WAITL(N)  asm volatile("s_waitcnt lgkmcnt(" #N ")" ::: "memory")
#define BAR()     __builtin_amdgcn_s_barrier()

// ---------------- pass 1: merged conversion ----------------
// blockIdx.y < NB : convert adapter ids[y] -> bf16 slot (dedup if by_id)
// blockIdx.y >= NB: convert half (y-NB) of x -> bf16
__global__ __launch_bounds__(256)
void cvt_all_kernel(const float* __restrict__ x, const float* __restrict__ w,
                    const int* __restrict__ ids, short* __restrict__ xo,
                    short* __restrict__ wo, int by_id)
{
    const int y = blockIdx.y;
    const int stride = gridDim.x * blockDim.x;
    if (y < NB) {
        const int id = ids[y];
        int slot = y;
        if (by_id) {
            for (int j = 0; j < y; ++j) if (ids[j] == id) return;  // dup handled
            slot = id;
        }
        const float* __restrict__ src = w + (size_t)id   * OUT_N * IN_K;
        short* __restrict__       dst = wo + (size_t)slot * OUT_N * IN_K;
        const int n8 = OUT_N * IN_K / 8;
        for (int i = blockIdx.x * blockDim.x + threadIdx.x; i < n8; i += stride) {
            const float4v a = *(const float4v*)(src + (size_t)i * 8);
            const float4v c = *(const float4v*)(src + (size_t)i * 8 + 4);
            *(short8*)(dst + (size_t)i * 8) = pack8(a, c);
        }
    } else {
        const int half = y - NB;                         // 0 or 1
        const int n8h  = NB * SEQ * IN_K / 16;           // half of x, in short8 units
        const float* __restrict__ src = x  + (size_t)half * n8h * 8;
        short* __restrict__       dst = xo + (size_t)half * n8h * 8;
        for (int i = blockIdx.x * blockDim.x + threadIdx.x; i < n8h; i += stride) {
            const float4v a = *(const float4v*)(src + (size_t)i * 8);
            const float4v c = *(const float4v*)(src + (size_t)i * 8 + 4);
            *(short8*)(dst + (size_t)i * 8) = pack8(a, c);
        }
    }
}

// ---------------- pass 2: 256^2 GEMM, 8-phase template (reduced barriers) ----------------
// A: [NB][SEQ][IN_K] bf16; W: bf16 adapter slots; slot = by_id ? ids[bz] : bz.
// Chunk layout [128 rows][8 x 16B slots]; LDS slot s holds global kslot s^(row&7).
__global__ __launch_bounds__(GT, 2)
void mll_gemm_v11(const short* __restrict__ A, const short* __restrict__ W,
                  const int* __restrict__ ids, int by_id, float* __restrict__ out)
{
    // [buf][chunk: 0=A0,1=A1,2=B0,3=B1][128*64 shorts] = 128 KiB
    __shared__ __align__(16) short lds[2][4][CH];

    const int tid  = threadIdx.x;
    const int lane = tid & 63;
    const int wid  = tid >> 6;    // 0..7
    const int wr   = wid >> 2;    // 0..1  (M half -> A chunk wr)
    const int wc   = wid & 3;     // 0..3  (N quarter -> B chunk 2+(wc>>1))

    // chunked XCD swizzle (512 blocks, 512 % 8 == 0 -> bijective)
    const int bid = blockIdx.x;
    const int n   = (bid & 7) * 64 + (bid >> 3);
    const int bx  = n & 15;          // OUT tile
    const int by  = (n >> 4) & 7;    // SEQ tile
    const int bz  = n >> 7;          // batch
    const int brow = by * BM, bcol = bx * BN;

    const int wslot = by_id ? ids[bz] : bz;
    const short* __restrict__ Ab = A + (size_t)bz * SEQ * IN_K + (size_t)brow * IN_K;
    const short* __restrict__ Bb = W + (size_t)wslot * OUT_N * IN_K + (size_t)bcol * IN_K;

    // staging: per chunk 1024 x 16B; thread covers c = tid + r*512, r=0,1.
    // c -> row c>>3, LDS slot c&7, global kslot (c&7)^(row&7). Linear LDS dest.
    const short* gA[2][2];   // [half][r]
    const short* gB[2][2];
    int ldso[2];
#pragma unroll
    for (int r = 0; r < 2; ++r) {
        const int c   = tid + r * GT;
        const int row = c >> 3;
        const int sg  = (c & 7) ^ (row & 7);
        ldso[r] = c * 8;
        gA[0][r] = Ab + (size_t)row         * IN_K + sg * 8;
        gA[1][r] = Ab + (size_t)(128 + row) * IN_K + sg * 8;
        gB[0][r] = Bb + (size_t)row         * IN_K + sg * 8;
        gB[1][r] = Bb + (size_t)(128 + row) * IN_K + sg * 8;
    }

#define STAGE_A(h, t) do { short* d_ = &lds[(t) & 1][h][0];                    \
        gload_lds16(gA[h][0] + (t) * BK, d_ + ldso[0]);                        \
        gload_lds16(gA[h][1] + (t) * BK, d_ + ldso[1]); } while (0)
#define STAGE_B(h, t) do { short* d_ = &lds[(t) & 1][2 + (h)][0];              \
        gload_lds16(gB[h][0] + (t) * BK, d_ + ldso[0]);                        \
        gload_lds16(gB[h][1] + (t) * BK, d_ + ldso[1]); } while (0)

    float4v acc[8][4];
#pragma unroll
    for (int m = 0; m < 8; ++m)
#pragma unroll
        for (int q = 0; q < 4; ++q)
            acc[m][q] = (float4v){0.f, 0.f, 0.f, 0.f};

    const int lr  = lane & 15;
    const int ksl = lane >> 4;                       // 16B slot within K=32 half
    const int sw  = lr & 7;
    const int so0 = ((0 + ksl) ^ sw) * 8;            // khalf 0 read offset (shorts)
    const int so1 = ((4 + ksl) ^ sw) * 8;            // khalf 1

    const int cA = wr;                 // this wave's A chunk
    const int cB = 2 + (wc >> 1);      // this wave's B chunk
    const int bRow0 = ((wc & 1) * 64 + lr) * BK;     // B row base (q adds q*16*BK)

    short8 fA[4][2], fBlo[2][2], fBhi[2][2];

    // ---- prologue: stage tiles 0 and 1 fully (16 loads) ----
    STAGE_A(0, 0); STAGE_A(1, 0); STAGE_B(0, 0); STAGE_B(1, 0);
    STAGE_A(0, 1); STAGE_A(1, 1); STAGE_B(0, 1); STAGE_B(1, 1);
    WAITV(8);                       // tile 0 certified; tile 1 in flight
    BAR();

    for (int t = 0; t < KT; ++t) {
        const short* sA = &lds[t & 1][cA][0];
        const short* sB = &lds[t & 1][cB][0];

        // ===== P1: read A(mlo)x2 + B(qlo)x2 (12); stage A0(t+1); MFMA mlo x qlo =====
#pragma unroll
        for (int m = 0; m < 4; ++m) {
            fA[m][0] = *(const short8*)(sA + (m * 16 + lr) * BK + so0);
            fA[m][1] = *(const short8*)(sA + (m * 16 + lr) * BK + so1);
        }
#pragma unroll
        for (int q = 0; q < 2; ++q) {
            fBlo[q][0] = *(const short8*)(sB + bRow0 + q * 16 * BK + so0);
            fBlo[q][1] = *(const short8*)(sB + bRow0 + q * 16 * BK + so1);
        }
        if (t >= 1 && t + 1 < KT) STAGE_A(0, t + 1);
        WAITL(8);                       // pre-drain hint (12 reads issued)
        BAR(); WAITL(0);
        __builtin_amdgcn_s_setprio(1);
#pragma unroll
        for (int m = 0; m < 4; ++m)
#pragma unroll
            for (int q = 0; q < 2; ++q) {
                acc[m][q] = __builtin_amdgcn_mfma_f32_16x16x32_bf16(
                    fA[m][0], fBlo[q][0], acc[m][q], 0, 0, 0);
                acc[m][q] = __builtin_amdgcn_mfma_f32_16x16x32_bf16(
                    fA[m][1], fBlo[q][1], acc[m][q], 0, 0, 0);
            }
        __builtin_amdgcn_s_setprio(0);
        // (closing barrier elided: next stage targets non-live buffer)

        // ===== P2: read B(qhi) (4); stage A1(t+1); MFMA mlo x qhi =====
#pragma unroll
        for (int q = 0; q < 2; ++q) {
            fBhi[q][0] = *(const short8*)(sB + bRow0 + (q + 2) * 16 * BK + so0);
            fBhi[q][1] = *(const short8*)(sB + bRow0 + (q + 2) * 16 * BK + so1);
        }
        if (t >= 1 && t + 1 < KT) STAGE_A(1, t + 1);
        BAR(); WAITL(0);
        __builtin_amdgcn_s_setprio(1);
#pragma unroll
        for (int m = 0; m < 4; ++m)
#pragma unroll
            for (int q = 0; q < 2; ++q) {
                acc[m][q + 2] = __builtin_amdgcn_mfma_f32_16x16x32_bf16(
                    fA[m][0], fBhi[q][0], acc[m][q + 2], 0, 0, 0);
                acc[m][q + 2] = __builtin_amdgcn_mfma_f32_16x16x32_bf16(
                    fA[m][1], fBhi[q][1], acc[m][q + 2], 0, 0, 0);
            }
        __builtin_amdgcn_s_setprio(0);
        BAR();   // KEPT: P3 stages B0(t+2) into the live buffer (same slot as B0(t))

        // ===== P3: read A(mhi) (8, reuse fA); stage B0(t+2); MFMA mhi x qhi =====
#pragma unroll
        for (int m = 0; m < 4; ++m) {
            fA[m][0] = *(const short8*)(sA + ((m + 4) * 16 + lr) * BK + so0);
            fA[m][1] = *(const short8*)(sA + ((m + 4) * 16 + lr) * BK + so1);
        }
        if (t + 2 < KT) STAGE_B(0, t + 2);
        WAITL(4);                       // pre-drain hint (8 reads issued)
        BAR(); WAITL(0);
        __builtin_amdgcn_s_setprio(1);
#pragma unroll
        for (int m = 0; m < 4; ++m)
#pragma unroll
            for (int q = 0; q < 2; ++q) {
                acc[m + 4][q + 2] = __builtin_amdgcn_mfma_f32_16x16x32_bf16(
                    fA[m][0], fBhi[q][0], acc[m + 4][q + 2], 0, 0, 0);
                acc[m + 4][q + 2] = __builtin_amdgcn_mfma_f32_16x16x32_bf16(
                    fA[m][1], fBhi[q][1], acc[m + 4][q + 2], 0, 0, 0);
            }
        __builtin_amdgcn_s_setprio(0);
        // (closing barrier elided: B1(t+2) stage ordered by BAR(P2)+BAR(P3))

        // ===== P4: no reads; stage B1(t+2); vmcnt; MFMA mhi x qlo =====
        if (t + 2 < KT) STAGE_B(1, t + 2);
        if (t <= KT - 3)      WAITV(4);   // certify tile t+1; leave B(t+2) in flight
        else if (t == KT - 2) WAITV(0);
        BAR();
        __builtin_amdgcn_s_setprio(1);
#pragma unroll
        for (int m = 0; m < 4; ++m)
#pragma unroll
            for (int q = 0; q < 2; ++q) {
                acc[m + 4][q] = __builtin_amdgcn_mfma_f32_16x16x32_bf16(
                    fA[m][0], fBlo[q][0], acc[m + 4][q], 0, 0, 0);
                acc[m + 4][q] = __builtin_amdgcn_mfma_f32_16x16x32_bf16(
                    fA[m][1], fBlo[q][1], acc[m + 4][q], 0, 0, 0);
            }
        __builtin_amdgcn_s_setprio(0);
        // (closing barrier elided: P1(t+1)'s A0(t+2) stage ordered by BAR(P4))
    }

    // epilogue: C/D layout col=lane&15, row=(lane>>4)*4+reg
    float* __restrict__ ob = out + (size_t)bz * SEQ * OUT_N;
    const int lrow = ksl * 4;
#pragma unroll
    for (int m = 0; m < 8; ++m) {
#pragma unroll
        for (int q = 0; q < 4; ++q) {
            const int r0 = brow + wr * 128 + m * 16 + lrow;
            const int c  = bcol + wc * 64 + q * 16 + lr;
#pragma unroll
            for (int j = 0; j < 4; ++j)
                ob[(size_t)(r0 + j) * OUT_N + c] = acc[m][q][j];
        }
    }
#undef STAGE_A
#undef STAGE_B
}

// ---------------- fallback: fused kernel (ws too small) ----------------
__device__ inline int xr(int row) { return (row & 3) ^ ((row >> 2) & 3); }

__global__ __launch_bounds__(256, 2)
void mll_gemm_fused(const float* __restrict__ x,
                    const float* __restrict__ w,
                    const int*   __restrict__ adapter_ids,
                    float* __restrict__ out)
{
    constexpr int FBM = 128, FBN = 128, FBK = 32;
    __shared__ __align__(16) short As[2][FBM * FBK];
    __shared__ __align__(16) short Bs[2][FBN * FBK];

    const int tid  = threadIdx.x;
    const int lane = tid & 63;
    const int wave = tid >> 6;
    const int wr   = wave >> 1;
    const int wc   = wave & 1;

    const int b    = blockIdx.z;
    const int aid  = adapter_ids[b];
    const int brow = blockIdx.y * FBM;
    const int bcol = blockIdx.x * FBN;

    const float* __restrict__ xb = x + (size_t)b   * SEQ   * IN_K;
    const float* __restrict__ wb = w + (size_t)aid * OUT_N * IN_K;

    float4v ra[2][2], rb[2][2];

    auto LOADG = [&](int kt) {
        const int k0 = kt * FBK;
#pragma unroll
        for (int g = 0; g < 2; ++g) {
            const int f  = tid + g * 256;
            const int r  = f >> 2;
            const int sl = f & 3;
            const float* pa = xb + (size_t)(brow + r) * IN_K + k0 + sl * 8;
            ra[g][0] = *(const float4v*)pa;
            ra[g][1] = *(const float4v*)(pa + 4);
            const float* pb = wb + (size_t)(bcol + r) * IN_K + k0 + sl * 8;
            rb[g][0] = *(const float4v*)pb;
            rb[g][1] = *(const float4v*)(pb + 4);
        }
    };
    auto STORE_LDS = [&](int buf) {
#pragma unroll
        for (int g = 0; g < 2; ++g) {
            const int f  = tid + g * 256;
            const int r  = f >> 2;
            const int sl = f & 3;
            const int ss = sl ^ xr(r);
            *(short8*)&As[buf][r * FBK + ss * 8] = pack8(ra[g][0], ra[g][1]);
            *(short8*)&Bs[buf][r * FBK + ss * 8] = pack8(rb[g][0], rb[g][1]);
        }
    };

    float4v acc[4][4];
#pragma unroll
    for (int m = 0; m < 4; ++m)
#pragma unroll
        for (int q = 0; q < 4; ++q)
            acc[m][q] = (float4v){0.f, 0.f, 0.f, 0.f};

    const int NT = IN_K / FBK;
    LOADG(0); STORE_LDS(0); __syncthreads();
    int cur = 0;
    for (int kt = 0; kt < NT; ++kt) {
        if (kt + 1 < NT) LOADG(kt + 1);
        short8 af[4], bfr[4];
        const int ksl = lane >> 4;
#pragma unroll
        for (int m = 0; m < 4; ++m) {
            const int rrk = wr * 64 + m * 16 + (lane & 15);
            af[m] = *(const short8*)&As[cur][rrk * FBK + (ksl ^ xr(rrk)) * 8];
        }
#pragma unroll
        for (int q = 0; q < 4; ++q) {
            const int rc = wc * 64 + q * 16 + (lane & 15);
            bfr[q] = *(const short8*)&Bs[cur][rc * FBK + (ksl ^ xr(rc)) * 8];
        }
#pragma unroll
        for (int m = 0; m < 4; ++m)
#pragma unroll
            for (int q = 0; q < 4; ++q)
                acc[m][q] = __builtin_amdgcn_mfma_f32_16x16x32_bf16(
                    af[m], bfr[q], acc[m][q], 0, 0, 0);
        if (kt + 1 < NT) STORE_LDS(cur ^ 1);
        __syncthreads();
        cur ^= 1;
    }

    float* __restrict__ ob = out + (size_t)b * SEQ * OUT_N;
    const int lrow = (lane >> 4) * 4;
    const int lcol = lane & 15;
#pragma unroll
    for (int m = 0; m < 4; ++m) {
#pragma unroll
        for (int q = 0; q < 4; ++q) {
            const int r0 = brow + wr * 64 + m * 16 + lrow;
            const int c  = bcol + wc * 64 + q * 16 + lcol;
#pragma unroll
            for (int j = 0; j < 4; ++j)
                ob[(size_t)(r0 + j) * OUT_N + c] = acc[m][q][j];
        }
    }
}

extern "C" void kernel_launch(void* const* d_in, const int* in_sizes, int n_in,
                              void* d_out, int out_size, void* d_ws, size_t ws_size,
                              hipStream_t stream)
{
    const float* x   = (const float*)d_in[0];
    const float* w   = (const float*)d_in[1];
    const int*   ids = (const int*)d_in[2];
    float* out = (float*)d_out;

    const size_t xb_bytes  = (size_t)NB * SEQ   * IN_K * sizeof(short);  //  64 MB
    const size_t wb4_bytes = (size_t)NB * OUT_N * IN_K * sizeof(short);  // 128 MB
    const size_t wb8_bytes = (size_t)8  * OUT_N * IN_K * sizeof(short);  // 256 MB

    if (ws_size >= xb_bytes + wb8_bytes) {          // id-indexed slots + dedup
        short* xb16 = (short*)d_ws;
        short* wb16 = (short*)((char*)d_ws + xb_bytes);
        cvt_all_kernel<<<dim3(1024, NB + 2), 256, 0, stream>>>(x, w, ids, xb16, wb16, 1);
        mll_gemm_v11<<<512, GT, 0, stream>>>(xb16, wb16, ids, 1, out);
    } else if (ws_size >= xb_bytes + wb4_bytes) {   // per-batch gather
        short* xb16 = (short*)d_ws;
        short* wb16 = (short*)((char*)d_ws + xb_bytes);
        cvt_all_kernel<<<dim3(1024, NB + 2), 256, 0, stream>>>(x, w, ids, xb16, wb16, 0);
        mll_gemm_v11<<<512, GT, 0, stream>>>(xb16, wb16, ids, 0, out);
    } else {
        mll_gemm_fused<<<dim3(OUT_N / 128, SEQ / 128, NB), 256, 0, stream>>>(
            x, w, ids, out);
    }
}

// Round 12
// 312.520 us; speedup vs baseline: 1.2041x; 1.0325x over previous
//
#include <hip/hip_runtime.h>
#include <hip/hip_bf16.h>

// MultiLoraLinear: out[b,s,o] = sum_i x[b,s,i] * weight[adapter_ids[b], o, i]
// B=4, S=2048, IN=4096, OUT=4096. fp32 in/out, bf16 MFMA compute.
// (1) one merged cvt kernel: x -> bf16 + referenced adapters -> bf16 id-slots,
// (2) 256x256 GEMM, BK=64, m201 8-phase schedule, minimal barrier set:
//     only P2-closer (guards live-buffer B stages) and P4 WAITV+BAR (tile
//     certification). Counted vmcnt(4), setprio around MFMA clusters.

#define SEQ    2048
#define IN_K   4096
#define OUT_N  4096
#define NB     4

typedef __attribute__((ext_vector_type(8))) short  short8;   // bf16x8 MFMA frag
typedef __attribute__((ext_vector_type(4))) float  float4v;

constexpr int BM = 256, BN = 256, BK = 64;
constexpr int GT = 512;                 // 8 waves
constexpr int KT = IN_K / BK;           // 64 K-tiles
constexpr int CH = 128 * 64;            // chunk size in shorts (16 KB)

// bf16 RNE from f32
__device__ inline short f2b(float f) {
    union { float f; unsigned u; } v; v.f = f;
    unsigned r = v.u + 0x7FFFu + ((v.u >> 16) & 1u);
    return (short)(r >> 16);
}
__device__ inline short8 pack8(float4v lo, float4v hi) {
    short8 r;
    r[0] = f2b(lo[0]); r[1] = f2b(lo[1]); r[2] = f2b(lo[2]); r[3] = f2b(lo[3]);
    r[4] = f2b(hi[0]); r[5] = f2b(hi[1]); r[6] = f2b(hi[2]); r[7] = f2b(hi[3]);
    return r;
}

typedef const __attribute__((address_space(1))) void* gp1_t;
typedef __attribute__((address_space(3))) void*       lp3_t;
__device__ inline void gload_lds16(const void* g, void* l) {
    __builtin_amdgcn_global_load_lds((gp1_t)g, (lp3_t)l, 16, 0, 0);
}

#define WAITV(N)  asm volatile("s_waitcnt vmcnt(" #N ")" ::: "memory")
#define WAITL(N)  asm volatile("s_waitcnt lgkmcnt(" #N ")" ::: "memory")
#define BAR()     __builtin_amdgcn_s_barrier()

// ---------------- pass 1: merged conversion ----------------
// blockIdx.y < NB : convert adapter ids[y] -> bf16 slot (dedup if by_id)
// blockIdx.y >= NB: convert half (y-NB) of x -> bf16
__global__ __launch_bounds__(256)
void cvt_all_kernel(const float* __restrict__ x, const float* __restrict__ w,
                    const int* __restrict__ ids, short* __restrict__ xo,
                    short* __restrict__ wo, int by_id)
{
    const int y = blockIdx.y;
    const int stride = gridDim.x * blockDim.x;
    if (y < NB) {
        const int id = ids[y];
        int slot = y;
        if (by_id) {
            for (int j = 0; j < y; ++j) if (ids[j] == id) return;  // dup handled
            slot = id;
        }
        const float* __restrict__ src = w + (size_t)id   * OUT_N * IN_K;
        short* __restrict__       dst = wo + (size_t)slot * OUT_N * IN_K;
        const int n8 = OUT_N * IN_K / 8;
        for (int i = blockIdx.x * blockDim.x + threadIdx.x; i < n8; i += stride) {
            const float4v a = *(const float4v*)(src + (size_t)i * 8);
            const float4v c = *(const float4v*)(src + (size_t)i * 8 + 4);
            *(short8*)(dst + (size_t)i * 8) = pack8(a, c);
        }
    } else {
        const int half = y - NB;                         // 0 or 1
        const int n8h  = NB * SEQ * IN_K / 16;           // half of x, in short8 units
        const float* __restrict__ src = x  + (size_t)half * n8h * 8;
        short* __restrict__       dst = xo + (size_t)half * n8h * 8;
        for (int i = blockIdx.x * blockDim.x + threadIdx.x; i < n8h; i += stride) {
            const float4v a = *(const float4v*)(src + (size_t)i * 8);
            const float4v c = *(const float4v*)(src + (size_t)i * 8 + 4);
            *(short8*)(dst + (size_t)i * 8) = pack8(a, c);
        }
    }
}

// ---------------- pass 2: 256^2 GEMM, 8-phase, minimal barriers ----------------
// A: [NB][SEQ][IN_K] bf16; W: bf16 adapter slots; slot = by_id ? ids[bz] : bz.
// Chunk layout [128 rows][8 x 16B slots]; LDS slot s holds global kslot s^(row&7).
__global__ __launch_bounds__(GT, 2)
void mll_gemm_v12(const short* __restrict__ A, const short* __restrict__ W,
                  const int* __restrict__ ids, int by_id, float* __restrict__ out)
{
    // [buf][chunk: 0=A0,1=A1,2=B0,3=B1][128*64 shorts] = 128 KiB
    __shared__ __align__(16) short lds[2][4][CH];

    const int tid  = threadIdx.x;
    const int lane = tid & 63;
    const int wid  = tid >> 6;    // 0..7
    const int wr   = wid >> 2;    // 0..1  (M half -> A chunk wr)
    const int wc   = wid & 3;     // 0..3  (N quarter -> B chunk 2+(wc>>1))

    // chunked XCD swizzle (512 blocks, 512 % 8 == 0 -> bijective)
    const int bid = blockIdx.x;
    const int n   = (bid & 7) * 64 + (bid >> 3);
    const int bx  = n & 15;          // OUT tile
    const int by  = (n >> 4) & 7;    // SEQ tile
    const int bz  = n >> 7;          // batch
    const int brow = by * BM, bcol = bx * BN;

    const int wslot = by_id ? ids[bz] : bz;
    const short* __restrict__ Ab = A + (size_t)bz * SEQ * IN_K + (size_t)brow * IN_K;
    const short* __restrict__ Bb = W + (size_t)wslot * OUT_N * IN_K + (size_t)bcol * IN_K;

    // staging: per chunk 1024 x 16B; thread covers c = tid + r*512, r=0,1.
    // c -> row c>>3, LDS slot c&7, global kslot (c&7)^(row&7). Linear LDS dest.
    const short* gA[2][2];   // [half][r]
    const short* gB[2][2];
    int ldso[2];
#pragma unroll
    for (int r = 0; r < 2; ++r) {
        const int c   = tid + r * GT;
        const int row = c >> 3;
        const int sg  = (c & 7) ^ (row & 7);
        ldso[r] = c * 8;
        gA[0][r] = Ab + (size_t)row         * IN_K + sg * 8;
        gA[1][r] = Ab + (size_t)(128 + row) * IN_K + sg * 8;
        gB[0][r] = Bb + (size_t)row         * IN_K + sg * 8;
        gB[1][r] = Bb + (size_t)(128 + row) * IN_K + sg * 8;
    }

#define STAGE_A(h, t) do { short* d_ = &lds[(t) & 1][h][0];                    \
        gload_lds16(gA[h][0] + (t) * BK, d_ + ldso[0]);                        \
        gload_lds16(gA[h][1] + (t) * BK, d_ + ldso[1]); } while (0)
#define STAGE_B(h, t) do { short* d_ = &lds[(t) & 1][2 + (h)][0];              \
        gload_lds16(gB[h][0] + (t) * BK, d_ + ldso[0]);                        \
        gload_lds16(gB[h][1] + (t) * BK, d_ + ldso[1]); } while (0)

    float4v acc[8][4];
#pragma unroll
    for (int m = 0; m < 8; ++m)
#pragma unroll
        for (int q = 0; q < 4; ++q)
            acc[m][q] = (float4v){0.f, 0.f, 0.f, 0.f};

    const int lr  = lane & 15;
    const int ksl = lane >> 4;                       // 16B slot within K=32 half
    const int sw  = lr & 7;
    const int so0 = ((0 + ksl) ^ sw) * 8;            // khalf 0 read offset (shorts)
    const int so1 = ((4 + ksl) ^ sw) * 8;            // khalf 1

    const int cA = wr;                 // this wave's A chunk
    const int cB = 2 + (wc >> 1);      // this wave's B chunk
    const int bRow0 = ((wc & 1) * 64 + lr) * BK;     // B row base (q adds q*16*BK)

    short8 fA[4][2], fBlo[2][2], fBhi[2][2];

    // ---- prologue: stage tiles 0 and 1 fully (16 loads) ----
    STAGE_A(0, 0); STAGE_A(1, 0); STAGE_B(0, 0); STAGE_B(1, 0);
    STAGE_A(0, 1); STAGE_A(1, 1); STAGE_B(0, 1); STAGE_B(1, 1);
    WAITV(8);                       // tile 0 certified; tile 1 in flight
    BAR();

    for (int t = 0; t < KT; ++t) {
        const short* sA = &lds[t & 1][cA][0];
        const short* sB = &lds[t & 1][cB][0];

        // ===== P1: read A(mlo)x2 + B(qlo)x2 (12); stage A0(t+1); MFMA mlo x qlo =====
        // (pre-MFMA barrier elided: tile t certified at P4(t-1); A0(t+1) stage
        //  guarded by P4(t-1) BAR -- prior readers drained at their P3 lgkm0)
#pragma unroll
        for (int m = 0; m < 4; ++m) {
            fA[m][0] = *(const short8*)(sA + (m * 16 + lr) * BK + so0);
            fA[m][1] = *(const short8*)(sA + (m * 16 + lr) * BK + so1);
        }
#pragma unroll
        for (int q = 0; q < 2; ++q) {
            fBlo[q][0] = *(const short8*)(sB + bRow0 + q * 16 * BK + so0);
            fBlo[q][1] = *(const short8*)(sB + bRow0 + q * 16 * BK + so1);
        }
        if (t >= 1 && t + 1 < KT) STAGE_A(0, t + 1);
        WAITL(0);
        __builtin_amdgcn_s_setprio(1);
#pragma unroll
        for (int m = 0; m < 4; ++m)
#pragma unroll
            for (int q = 0; q < 2; ++q) {
                acc[m][q] = __builtin_amdgcn_mfma_f32_16x16x32_bf16(
                    fA[m][0], fBlo[q][0], acc[m][q], 0, 0, 0);
                acc[m][q] = __builtin_amdgcn_mfma_f32_16x16x32_bf16(
                    fA[m][1], fBlo[q][1], acc[m][q], 0, 0, 0);
            }
        __builtin_amdgcn_s_setprio(0);

        // ===== P2: read B(qhi) (4); stage A1(t+1); MFMA mlo x qhi =====
#pragma unroll
        for (int q = 0; q < 2; ++q) {
            fBhi[q][0] = *(const short8*)(sB + bRow0 + (q + 2) * 16 * BK + so0);
            fBhi[q][1] = *(const short8*)(sB + bRow0 + (q + 2) * 16 * BK + so1);
        }
        if (t >= 1 && t + 1 < KT) STAGE_A(1, t + 1);
        WAITL(0);
        __builtin_amdgcn_s_setprio(1);
#pragma unroll
        for (int m = 0; m < 4; ++m)
#pragma unroll
            for (int q = 0; q < 2; ++q) {
                acc[m][q + 2] = __builtin_amdgcn_mfma_f32_16x16x32_bf16(
                    fA[m][0], fBhi[q][0], acc[m][q + 2], 0, 0, 0);
                acc[m][q + 2] = __builtin_amdgcn_mfma_f32_16x16x32_bf16(
                    fA[m][1], fBhi[q][1], acc[m][q + 2], 0, 0, 0);
            }
        __builtin_amdgcn_s_setprio(0);
        BAR();   // KEPT: all waves' B(t) frag-reads drained (own lgkm0 above)
                 // before P3/P4 stage B(t+2) into this live buffer

        // ===== P3: read A(mhi) (8, reuse fA); stage B0(t+2); MFMA mhi x qhi =====
#pragma unroll
        for (int m = 0; m < 4; ++m) {
            fA[m][0] = *(const short8*)(sA + ((m + 4) * 16 + lr) * BK + so0);
            fA[m][1] = *(const short8*)(sA + ((m + 4) * 16 + lr) * BK + so1);
        }
        if (t + 2 < KT) STAGE_B(0, t + 2);
        WAITL(0);
        __builtin_amdgcn_s_setprio(1);
#pragma unroll
        for (int m = 0; m < 4; ++m)
#pragma unroll
            for (int q = 0; q < 2; ++q) {
                acc[m + 4][q + 2] = __builtin_amdgcn_mfma_f32_16x16x32_bf16(
                    fA[m][0], fBhi[q][0], acc[m + 4][q + 2], 0, 0, 0);
                acc[m + 4][q + 2] = __builtin_amdgcn_mfma_f32_16x16x32_bf16(
                    fA[m][1], fBhi[q][1], acc[m + 4][q + 2], 0, 0, 0);
            }
        __builtin_amdgcn_s_setprio(0);

        // ===== P4: no reads; stage B1(t+2); vmcnt; certify tile t+1; MFMA mhi x qlo =====
        if (t + 2 < KT) STAGE_B(1, t + 2);
        if (t <= KT - 3)      WAITV(4);   // drain tile t+1's 8 loads; keep B(t+2)
        else if (t == KT - 2) WAITV(0);
        BAR();   // KEPT: collective certification of tile t+1
        __builtin_amdgcn_s_setprio(1);
#pragma unroll
        for (int m = 0; m < 4; ++m)
#pragma unroll
            for (int q = 0; q < 2; ++q) {
                acc[m + 4][q] = __builtin_amdgcn_mfma_f32_16x16x32_bf16(
                    fA[m][0], fBlo[q][0], acc[m + 4][q], 0, 0, 0);
                acc[m + 4][q] = __builtin_amdgcn_mfma_f32_16x16x32_bf16(
                    fA[m][1], fBlo[q][1], acc[m + 4][q], 0, 0, 0);
            }
        __builtin_amdgcn_s_setprio(0);
    }

    // epilogue: C/D layout col=lane&15, row=(lane>>4)*4+reg
    float* __restrict__ ob = out + (size_t)bz * SEQ * OUT_N;
    const int lrow = ksl * 4;
#pragma unroll
    for (int m = 0; m < 8; ++m) {
#pragma unroll
        for (int q = 0; q < 4; ++q) {
            const int r0 = brow + wr * 128 + m * 16 + lrow;
            const int c  = bcol + wc * 64 + q * 16 + lr;
#pragma unroll
            for (int j = 0; j < 4; ++j)
                ob[(size_t)(r0 + j) * OUT_N + c] = acc[m][q][j];
        }
    }
#undef STAGE_A
#undef STAGE_B
}

// ---------------- fallback: fused kernel (ws too small) ----------------
__device__ inline int xr(int row) { return (row & 3) ^ ((row >> 2) & 3); }

__global__ __launch_bounds__(256, 2)
void mll_gemm_fused(const float* __restrict__ x,
                    const float* __restrict__ w,
                    const int*   __restrict__ adapter_ids,
                    float* __restrict__ out)
{
    constexpr int FBM = 128, FBN = 128, FBK = 32;
    __shared__ __align__(16) short As[2][FBM * FBK];
    __shared__ __align__(16) short Bs[2][FBN * FBK];

    const int tid  = threadIdx.x;
    const int lane = tid & 63;
    const int wave = tid >> 6;
    const int wr   = wave >> 1;
    const int wc   = wave & 1;

    const int b    = blockIdx.z;
    const int aid  = adapter_ids[b];
    const int brow = blockIdx.y * FBM;
    const int bcol = blockIdx.x * FBN;

    const float* __restrict__ xb = x + (size_t)b   * SEQ   * IN_K;
    const float* __restrict__ wb = w + (size_t)aid * OUT_N * IN_K;

    float4v ra[2][2], rb[2][2];

    auto LOADG = [&](int kt) {
        const int k0 = kt * FBK;
#pragma unroll
        for (int g = 0; g < 2; ++g) {
            const int f  = tid + g * 256;
            const int r  = f >> 2;
            const int sl = f & 3;
            const float* pa = xb + (size_t)(brow + r) * IN_K + k0 + sl * 8;
            ra[g][0] = *(const float4v*)pa;
            ra[g][1] = *(const float4v*)(pa + 4);
            const float* pb = wb + (size_t)(bcol + r) * IN_K + k0 + sl * 8;
            rb[g][0] = *(const float4v*)pb;
            rb[g][1] = *(const float4v*)(pb + 4);
        }
    };
    auto STORE_LDS = [&](int buf) {
#pragma unroll
        for (int g = 0; g < 2; ++g) {
            const int f  = tid + g * 256;
            const int r  = f >> 2;
            const int sl = f & 3;
            const int ss = sl ^ xr(r);
            *(short8*)&As[buf][r * FBK + ss * 8] = pack8(ra[g][0], ra[g][1]);
            *(short8*)&Bs[buf][r * FBK + ss * 8] = pack8(rb[g][0], rb[g][1]);
        }
    };

    float4v acc[4][4];
#pragma unroll
    for (int m = 0; m < 4; ++m)
#pragma unroll
        for (int q = 0; q < 4; ++q)
            acc[m][q] = (float4v){0.f, 0.f, 0.f, 0.f};

    const int NT = IN_K / FBK;
    LOADG(0); STORE_LDS(0); __syncthreads();
    int cur = 0;
    for (int kt = 0; kt < NT; ++kt) {
        if (kt + 1 < NT) LOADG(kt + 1);
        short8 af[4], bfr[4];
        const int ksl = lane >> 4;
#pragma unroll
        for (int m = 0; m < 4; ++m) {
            const int rrk = wr * 64 + m * 16 + (lane & 15);
            af[m] = *(const short8*)&As[cur][rrk * FBK + (ksl ^ xr(rrk)) * 8];
        }
#pragma unroll
        for (int q = 0; q < 4; ++q) {
            const int rc = wc * 64 + q * 16 + (lane & 15);
            bfr[q] = *(const short8*)&Bs[cur][rc * FBK + (ksl ^ xr(rc)) * 8];
        }
#pragma unroll
        for (int m = 0; m < 4; ++m)
#pragma unroll
            for (int q = 0; q < 4; ++q)
                acc[m][q] = __builtin_amdgcn_mfma_f32_16x16x32_bf16(
                    af[m], bfr[q], acc[m][q], 0, 0, 0);
        if (kt + 1 < NT) STORE_LDS(cur ^ 1);
        __syncthreads();
        cur ^= 1;
    }

    float* __restrict__ ob = out + (size_t)b * SEQ * OUT_N;
    const int lrow = (lane >> 4) * 4;
    const int lcol = lane & 15;
#pragma unroll
    for (int m = 0; m < 4; ++m) {
#pragma unroll
        for (int q = 0; q < 4; ++q) {
            const int r0 = brow + wr * 64 + m * 16 + lrow;
            const int c  = bcol + wc * 64 + q * 16 + lcol;
#pragma unroll
            for (int j = 0; j < 4; ++j)
                ob[(size_t)(r0 + j) * OUT_N + c] = acc[m][q][j];
        }
    }
}

extern "C" void kernel_launch(void* const* d_in, const int* in_sizes, int n_in,
                              void* d_out, int out_size, void* d_ws, size_t ws_size,
                              hipStream_t stream)
{
    const float* x   = (const float*)d_in[0];
    const float* w   = (const float*)d_in[1];
    const int*   ids = (const int*)d_in[2];
    float* out = (float*)d_out;

    const size_t xb_bytes  = (size_t)NB * SEQ   * IN_K * sizeof(short);  //  64 MB
    const size_t wb4_bytes = (size_t)NB * OUT_N * IN_K * sizeof(short);  // 128 MB
    const size_t wb8_bytes = (size_t)8  * OUT_N * IN_K * sizeof(short);  // 256 MB

    if (ws_size >= xb_bytes + wb8_bytes) {          // id-indexed slots + dedup
        short* xb16 = (short*)d_ws;
        short* wb16 = (short*)((char*)d_ws + xb_bytes);
        cvt_all_kernel<<<dim3(1024, NB + 2), 256, 0, stream>>>(x, w, ids, xb16, wb16, 1);
        mll_gemm_v12<<<512, GT, 0, stream>>>(xb16, wb16, ids, 1, out);
    } else if (ws_size >= xb_bytes + wb4_bytes) {   // per-batch gather
        short* xb16 = (short*)d_ws;
        short* wb16 = (short*)((char*)d_ws + xb_bytes);
        cvt_all_kernel<<<dim3(1024, NB + 2), 256, 0, stream>>>(x, w, ids, xb16, wb16, 0);
        mll_gemm_v12<<<512, GT, 0, stream>>>(xb16, wb16, ids, 0, out);
    } else {
        mll_gemm_fused<<<dim3(OUT_N / 128, SEQ / 128, NB), 256, 0, stream>>>(
            x, w, ids, out);
    }
}